// Round 9
// baseline (176.194 us; speedup 1.0000x reference)
//
#include <hip/hip_runtime.h>
#include <hip/hip_bf16.h>

// Problem constants
#define SEQ   2048
#define INF_  512          // IN dim
#define HQ    16           // query heads
#define KVH   4            // kv heads
#define DH    64           // head dim
#define NQ    (HQ*DH)      // 1024
#define NKV   (KVH*DH)     // 256
#define OUTD  512

typedef short v8s __attribute__((ext_vector_type(8)));   // 8 bf16 (4 VGPRs)
typedef float v4f __attribute__((ext_vector_type(4)));   // 4 fp32 acc

static __device__ __forceinline__ float bf2f(unsigned short u) {
    union { unsigned int i; float f; } c;
    c.i = ((unsigned int)u) << 16;
    return c.f;
}
static __device__ __forceinline__ unsigned short f2bf(float f) {  // RNE
    union { float f; unsigned int i; } c; c.f = f;
    unsigned int lsb = (c.i >> 16) & 1u;
    c.i += 0x7fffu + lsb;
    return (unsigned short)(c.i >> 16);
}
static __device__ __forceinline__ unsigned int f2bf2(float lo, float hi) { // packed cvt
    union { __hip_bfloat162 h; unsigned int u; } c;
    c.h = __float22bfloat162_rn(make_float2(lo, hi));
    return c.u;
}
static __device__ __forceinline__ unsigned int addbf2(unsigned int a, unsigned int b) {
    float lo = bf2f((unsigned short)(a & 0xffffu)) + bf2f((unsigned short)(b & 0xffffu));
    float hi = bf2f((unsigned short)(a >> 16))     + bf2f((unsigned short)(b >> 16));
    return f2bf2(lo, hi);
}

// async global->LDS DMA, 16B per lane; lds base must be lane-invariant
static __device__ __forceinline__ void gll16(const void* g, void* l) {
    __builtin_amdgcn_global_load_lds(
        (const __attribute__((address_space(1))) void*)g,
        (__attribute__((address_space(3))) void*)l, 16, 0, 0);
}

// ===========================================================================
// GEMM 1 (MFMA): QKV projection, fp32 in -> bf16 swizzled tile buffers.
// 64x64 tile, BK=64, register prefetch, 2x2 waves. Grid 32x24 = 768 blocks.
// Tile format (4096 elems = 64 rows x 8 groups x 8): group swizzled by row&7.
//   Qg[st][h]: row=q&63, grp=(d>>3)^(q&7), off=d&7   (pre-scaled by 1/8)
//   Kg[g][t] : row=j&63, grp=(d>>3)^(j&7), off=d&7
//   Vg[g][t] : row=d,    grp=((j&63)>>3)^(d&7), off=j&7
// ===========================================================================
__global__ __launch_bounds__(256, 4) void gemm_qkv(
    const float* __restrict__ x,
    const float* __restrict__ Wq,
    const float* __restrict__ Wk,
    const float* __restrict__ Wv,
    unsigned short* __restrict__ Qg,
    unsigned short* __restrict__ Kg,
    unsigned short* __restrict__ Vg)
{
    __shared__ unsigned short Asb[64][72];
    __shared__ unsigned short Bsb[64][72];

    const int m0 = blockIdx.x * 64;
    const int n0 = blockIdx.y * 64;

    const float* Bp; int role;   // 0=Q 1=K 2=V
    if (n0 < NQ)            { Bp = Wq + (size_t)n0 * INF_;              role = 0; }
    else if (n0 < NQ + NKV) { Bp = Wk + (size_t)(n0 - NQ) * INF_;       role = 1; }
    else                    { Bp = Wv + (size_t)(n0 - NQ - NKV) * INF_; role = 2; }

    const int tid = threadIdx.x;
    const int w = tid >> 6, lane = tid & 63;
    const int n = lane & 15, quad = lane >> 4;
    const int r0w = (w & 1) * 32, c0w = (w >> 1) * 32;
    const int sr = tid >> 2, skc = (tid & 3) * 16;

    v4f acc[2][2];
#pragma unroll
    for (int rt = 0; rt < 2; rt++)
#pragma unroll
        for (int ct = 0; ct < 2; ct++) acc[rt][ct] = (v4f){0.f,0.f,0.f,0.f};

    const float* ap = x  + (size_t)(m0 + sr) * INF_ + skc;
    const float* bp = Bp + (size_t)sr * INF_ + skc;

    float4 pa[4], pb[4];
#pragma unroll
    for (int i = 0; i < 4; i++) {
        pa[i] = *(const float4*)(ap + 4 * i);
        pb[i] = *(const float4*)(bp + 4 * i);
    }

    for (int kb = 0; kb < INF_; kb += 64) {
        __syncthreads();
        *(uint4*)&Asb[sr][skc]     = make_uint4(f2bf2(pa[0].x,pa[0].y), f2bf2(pa[0].z,pa[0].w),
                                                f2bf2(pa[1].x,pa[1].y), f2bf2(pa[1].z,pa[1].w));
        *(uint4*)&Asb[sr][skc + 8] = make_uint4(f2bf2(pa[2].x,pa[2].y), f2bf2(pa[2].z,pa[2].w),
                                                f2bf2(pa[3].x,pa[3].y), f2bf2(pa[3].z,pa[3].w));
        *(uint4*)&Bsb[sr][skc]     = make_uint4(f2bf2(pb[0].x,pb[0].y), f2bf2(pb[0].z,pb[0].w),
                                                f2bf2(pb[1].x,pb[1].y), f2bf2(pb[1].z,pb[1].w));
        *(uint4*)&Bsb[sr][skc + 8] = make_uint4(f2bf2(pb[2].x,pb[2].y), f2bf2(pb[2].z,pb[2].w),
                                                f2bf2(pb[3].x,pb[3].y), f2bf2(pb[3].z,pb[3].w));
        __syncthreads();
        if (kb + 64 < INF_) {
#pragma unroll
            for (int i = 0; i < 4; i++) {
                pa[i] = *(const float4*)(ap + kb + 64 + 4 * i);
                pb[i] = *(const float4*)(bp + kb + 64 + 4 * i);
            }
        }
#pragma unroll
        for (int kk = 0; kk < 2; kk++) {
            v8s a0 = *(const v8s*)&Asb[r0w + n][kk * 32 + quad * 8];
            v8s a1 = *(const v8s*)&Asb[r0w + 16 + n][kk * 32 + quad * 8];
            v8s b0 = *(const v8s*)&Bsb[c0w + n][kk * 32 + quad * 8];
            v8s b1 = *(const v8s*)&Bsb[c0w + 16 + n][kk * 32 + quad * 8];
            acc[0][0] = __builtin_amdgcn_mfma_f32_16x16x32_bf16(a0, b0, acc[0][0], 0, 0, 0);
            acc[0][1] = __builtin_amdgcn_mfma_f32_16x16x32_bf16(a0, b1, acc[0][1], 0, 0, 0);
            acc[1][0] = __builtin_amdgcn_mfma_f32_16x16x32_bf16(a1, b0, acc[1][0], 0, 0, 0);
            acc[1][1] = __builtin_amdgcn_mfma_f32_16x16x32_bf16(a1, b1, acc[1][1], 0, 0, 0);
        }
    }

    const int t = m0 >> 6;
    if (role == 0) {
        unsigned short* base = Qg + ((size_t)(t * 16 + (n0 >> 6))) * 4096;
#pragma unroll
        for (int rt = 0; rt < 2; rt++)
#pragma unroll
            for (int ct = 0; ct < 2; ct++)
#pragma unroll
                for (int reg = 0; reg < 4; reg++) {
                    const int r = r0w + rt * 16 + quad * 4 + reg;
                    const int d = c0w + ct * 16 + n;
                    base[r * 64 + (((d >> 3) ^ (r & 7)) * 8) + (d & 7)] =
                        f2bf(acc[rt][ct][reg] * 0.125f);
                }
    } else if (role == 1) {
        const int g = (n0 - NQ) >> 6;
        unsigned short* base = Kg + ((size_t)(g * 32 + t)) * 4096;
#pragma unroll
        for (int rt = 0; rt < 2; rt++)
#pragma unroll
            for (int ct = 0; ct < 2; ct++)
#pragma unroll
                for (int reg = 0; reg < 4; reg++) {
                    const int r = r0w + rt * 16 + quad * 4 + reg;
                    const int d = c0w + ct * 16 + n;
                    base[r * 64 + (((d >> 3) ^ (r & 7)) * 8) + (d & 7)] =
                        f2bf(acc[rt][ct][reg]);
                }
    } else {
        const int g = (n0 - NQ - NKV) >> 6;
        unsigned short* base = Vg + ((size_t)(g * 32 + t)) * 4096;
#pragma unroll
        for (int rt = 0; rt < 2; rt++)
#pragma unroll
            for (int ct = 0; ct < 2; ct++) {
                const int jb_ = r0w + rt * 16 + quad * 4;  // 4 consecutive j
                const int d = c0w + ct * 16 + n;
                const int grp = (jb_ >> 3) ^ (d & 7);
                *(uint2*)&base[d * 64 + grp * 8 + (jb_ & 7)] =
                    make_uint2(f2bf2(acc[rt][ct][0], acc[rt][ct][1]),
                               f2bf2(acc[rt][ct][2], acc[rt][ct][3]));
            }
    }
}

// ===========================================================================
// MFMA flash attention, S^T formulation, max-free softmax, DMA staging.
// Block = 128 q-rows x head x g-pair; 4 waves x 32 rows. 512 blocks;
// qi2 = gp ? 15-jb : jb balances the (bx, bx+256) CU pairs.
// LDS 48KB: Q[128x64] (overlaid by per-wave PsT after frag load) +
// K dbuf 2x4KB + V dbuf 2x4KB. All frag reads conflict-free via XOR swizzle.
// ===========================================================================
__global__ __launch_bounds__(256, 2) void attn_mfma(
    const unsigned short* __restrict__ Qg,
    const unsigned short* __restrict__ Kg,
    const unsigned short* __restrict__ Vg,
    unsigned short* __restrict__ Oh0,
    unsigned short* __restrict__ Oh1)
{
    __shared__ unsigned short QsP[8192];      // Q staging, then per-wave PsT
    __shared__ unsigned short Ksb[2][4096];
    __shared__ unsigned short Vsb[2][4096];

    const int bx  = blockIdx.x;
    const int h   = bx & 15;
    const int jb  = (bx >> 4) & 15;
    const int gp  = bx >> 8;
    const int qi2 = gp ? (15 - jb) : jb;
    const int q0  = qi2 * 128;
    const int tid = threadIdx.x;
    const int w = tid >> 6, lane = tid & 63;
    const int n = lane & 15, quad = lane >> 4;
    const int r0 = w * 32;
    const int m7 = n & 7;
    const int g0 = gp * 2;

    // DMA: Q (4 instr/wave) + first K/V tile (2+2 instr/wave)
    {
        const unsigned short* qsrc =
            Qg + ((size_t)((2 * qi2 + (w >> 1)) * 16 + h)) * 4096 + (w & 1) * 2048 + lane * 8;
#pragma unroll
        for (int i = 0; i < 4; i++)
            gll16(qsrc + i * 512, &QsP[w * 2048 + i * 512]);
        const size_t kvoff = ((size_t)(g0 * 32)) * 4096 + w * 1024 + lane * 8;
#pragma unroll
        for (int i = 0; i < 2; i++) {
            gll16(Kg + kvoff + i * 512, &Ksb[0][w * 1024 + i * 512]);
            gll16(Vg + kvoff + i * 512, &Vsb[0][w * 1024 + i * 512]);
        }
    }
    __syncthreads();   // drain DMA (compiler emits vmcnt(0) before s_barrier)

    // Q B-fragments (loop-invariant)
    v8s qf[2][2];
#pragma unroll
    for (int qt = 0; qt < 2; qt++) {
        const int row = (r0 + qt * 16 + n) * 64;
        qf[qt][0] = *(const v8s*)&QsP[row + ((quad ^ m7) * 8)];
        qf[qt][1] = *(const v8s*)&QsP[row + (((quad + 4) ^ m7) * 8)];
    }
    unsigned short* Pw = &QsP[w * 2048];   // per-wave P region (overlays Q)

    v4f Ofin[2][4];
#pragma unroll
    for (int qt = 0; qt < 2; qt++)
#pragma unroll
        for (int dt = 0; dt < 4; dt++) Ofin[qt][dt] = (v4f){0.f,0.f,0.f,0.f};

    const int ntile = 2 * qi2 + 2;
    const v4f z = (v4f){0.f,0.f,0.f,0.f};
    int tc = 0;   // absolute tile counter; buffer = tc&1

    for (int gg = 0; gg < 2; gg++) {
        const int g = g0 + gg;
        float lst[2] = {0.f, 0.f};
        v4f Oacc[2][4];
#pragma unroll
        for (int qt = 0; qt < 2; qt++)
#pragma unroll
            for (int dt = 0; dt < 4; dt++) Oacc[qt][dt] = (v4f){0.f,0.f,0.f,0.f};

        for (int tt = 0; tt < ntile; tt++, tc++) {
            const int buf = tc & 1;
            __syncthreads();   // all waves done with buf^1; drains loads(tc)

            // issue DMA for the next tile (or next g's tile 0)
            {
                int ng = -1, nt = 0;
                if (tt + 1 < ntile)      { ng = g;     nt = tt + 1; }
                else if (gg == 0)        { ng = g + 1; nt = 0;      }
                if (ng >= 0) {
                    const int nbuf = (tc + 1) & 1;
                    const size_t off = ((size_t)(ng * 32 + nt)) * 4096 + w * 1024 + lane * 8;
                    gll16(Kg + off,       &Ksb[nbuf][w * 1024]);
                    gll16(Kg + off + 512, &Ksb[nbuf][w * 1024 + 512]);
                    gll16(Vg + off,       &Vsb[nbuf][w * 1024]);
                    gll16(Vg + off + 512, &Vsb[nbuf][w * 1024 + 512]);
                }
            }

            const int t0 = tt * 64;
            const bool do0 = (t0 <= q0 + r0 + 15);
            const bool do1 = (t0 <= q0 + r0 + 31);
            if (!do1) continue;

            const unsigned short* Kb = Ksb[buf];
            const unsigned short* Vb = Vsb[buf];

            // S^T = K·Q^T
            v4f sc[2][4];
#pragma unroll
            for (int jt = 0; jt < 4; jt++) {
                const int krow = (jt * 16 + n) * 64;
                v8s kf0 = *(const v8s*)&Kb[krow + ((quad ^ m7) * 8)];
                v8s kf1 = *(const v8s*)&Kb[krow + (((quad + 4) ^ m7) * 8)];
                if (do0) {
                    v4f tq = __builtin_amdgcn_mfma_f32_16x16x32_bf16(kf0, qf[0][0], z, 0, 0, 0);
                    sc[0][jt] = __builtin_amdgcn_mfma_f32_16x16x32_bf16(kf1, qf[0][1], tq, 0, 0, 0);
                }
                v4f t1 = __builtin_amdgcn_mfma_f32_16x16x32_bf16(kf0, qf[1][0], z, 0, 0, 0);
                sc[1][jt] = __builtin_amdgcn_mfma_f32_16x16x32_bf16(kf1, qf[1][1], t1, 0, 0, 0);
            }

            // mask (diagonal region) + exp + per-lane l + swizzled P b64 write
#pragma unroll
            for (int qt = 0; qt < 2; qt++) {
                if (qt == 0 && !do0) continue;
                const int qg = q0 + r0 + qt * 16 + n;
                if (t0 + 63 > q0 + r0 + qt * 16) {
#pragma unroll
                    for (int jt = 0; jt < 4; jt++) {
                        const int jg = t0 + jt * 16 + quad * 4;
#pragma unroll
                        for (int reg = 0; reg < 4; reg++)
                            sc[qt][jt][reg] = (jg + reg <= qg) ? sc[qt][jt][reg] : -INFINITY;
                    }
                }
                const int prow = (qt * 16 + n) * 64;
#pragma unroll
                for (int jt = 0; jt < 4; jt++) {
                    float p0 = __expf(sc[qt][jt][0]);
                    float p1 = __expf(sc[qt][jt][1]);
                    float p2 = __expf(sc[qt][jt][2]);
                    float p3 = __expf(sc[qt][jt][3]);
                    lst[qt] += (p0 + p1) + (p2 + p3);
                    *(uint2*)&Pw[prow + (((jt * 4 + quad) ^ (2 * m7)) * 4)] =
                        make_uint2(f2bf2(p0, p1), f2bf2(p2, p3));
                }
            }

            // PV: O^T = V^T · P^T (per-wave P, no barrier)
            v8s pf[2][2];
            if (do0) {
                const int pr = n * 64;
                pf[0][0] = *(const v8s*)&Pw[pr + (((2 * quad) ^ (2 * m7)) * 4)];
                pf[0][1] = *(const v8s*)&Pw[pr + (((8 + 2 * quad) ^ (2 * m7)) * 4)];
            }
            {
                const int pr = (16 + n) * 64;
                pf[1][0] = *(const v8s*)&Pw[pr + (((2 * quad) ^ (2 * m7)) * 4)];
                pf[1][1] = *(const v8s*)&Pw[pr + (((8 + 2 * quad) ^ (2 * m7)) * 4)];
            }
#pragma unroll
            for (int dt = 0; dt < 4; dt++) {
                const int vrow = (dt * 16 + n) * 64;
                v8s vf0 = *(const v8s*)&Vb[vrow + ((quad ^ m7) * 8)];
                v8s vf1 = *(const v8s*)&Vb[vrow + (((quad + 4) ^ m7) * 8)];
                if (do0) {
                    Oacc[0][dt] = __builtin_amdgcn_mfma_f32_16x16x32_bf16(vf0, pf[0][0], Oacc[0][dt], 0, 0, 0);
                    Oacc[0][dt] = __builtin_amdgcn_mfma_f32_16x16x32_bf16(vf1, pf[0][1], Oacc[0][dt], 0, 0, 0);
                }
                Oacc[1][dt] = __builtin_amdgcn_mfma_f32_16x16x32_bf16(vf0, pf[1][0], Oacc[1][dt], 0, 0, 0);
                Oacc[1][dt] = __builtin_amdgcn_mfma_f32_16x16x32_bf16(vf1, pf[1][1], Oacc[1][dt], 0, 0, 0);
            }
        }

        // fold g into average (l per lane; reduce across the 4 quads)
#pragma unroll
        for (int qt = 0; qt < 2; qt++) {
            float L = lst[qt];
            L += __shfl_xor(L, 16);
            L += __shfl_xor(L, 32);
            const float inv = 0.25f / L;
#pragma unroll
            for (int dt = 0; dt < 4; dt++)
#pragma unroll
                for (int reg = 0; reg < 4; reg++)
                    Ofin[qt][dt][reg] += Oacc[qt][dt][reg] * inv;
        }
    }

    // store O (bf16): lane holds 4 consecutive d per (qt,dt) -> b64
    unsigned short* Ohp = gp ? Oh1 : Oh0;
#pragma unroll
    for (int qt = 0; qt < 2; qt++) {
        const int row = q0 + r0 + qt * 16 + n;
        unsigned short* dst = Ohp + (size_t)row * NQ + h * DH + quad * 4;
#pragma unroll
        for (int dt = 0; dt < 4; dt++) {
            uint2 pk = make_uint2(f2bf2(Ofin[qt][dt][0], Ofin[qt][dt][1]),
                                  f2bf2(Ofin[qt][dt][2], Ofin[qt][dt][3]));
            *(uint2*)(dst + dt * 16) = pk;
        }
    }
}

// ===========================================================================
// GEMM 2 (MFMA): out[s][o] = sum_j (Oh0+Oh1)[s][j] * Wo[o][j]. fp32 out.
// 64x64 tile, BK=64, register prefetch. Grid 32x8 = 256 blocks.
// ===========================================================================
__global__ __launch_bounds__(256, 4) void gemm_out(
    const unsigned short* __restrict__ Oh0,
    const unsigned short* __restrict__ Oh1,
    const float* __restrict__ Wo,
    float* __restrict__ C)
{
    __shared__ unsigned short Asb[64][72];
    __shared__ unsigned short Bsb[64][72];

    const int m0 = blockIdx.x * 64;
    const int n0 = blockIdx.y * 64;
    const int tid = threadIdx.x;
    const int w = tid >> 6, lane = tid & 63;
    const int n = lane & 15, quad = lane >> 4;
    const int r0w = (w & 1) * 32, c0w = (w >> 1) * 32;
    const int sr = tid >> 2, skc = (tid & 3) * 16;

    v4f acc[2][2];
#pragma unroll
    for (int rt = 0; rt < 2; rt++)
#pragma unroll
        for (int ct = 0; ct < 2; ct++) acc[rt][ct] = (v4f){0.f,0.f,0.f,0.f};

    const unsigned short* a0p = Oh0 + (size_t)(m0 + sr) * NQ + skc;
    const unsigned short* a1p = Oh1 + (size_t)(m0 + sr) * NQ + skc;
    const float* bp = Wo + (size_t)(n0 + sr) * NQ + skc;

    uint4 ua0 = *(const uint4*)(a0p),     ua1 = *(const uint4*)(a0p + 8);
    uint4 ub0 = *(const uint4*)(a1p),     ub1 = *(const uint4*)(a1p + 8);
    float4 pb[4];
#pragma unroll
    for (int i = 0; i < 4; i++) pb[i] = *(const float4*)(bp + 4 * i);

    for (int kb = 0; kb < NQ; kb += 64) {
        __syncthreads();
        *(uint4*)&Asb[sr][skc]     = make_uint4(addbf2(ua0.x, ub0.x), addbf2(ua0.y, ub0.y),
                                                addbf2(ua0.z, ub0.z), addbf2(ua0.w, ub0.w));
        *(uint4*)&Asb[sr][skc + 8] = make_uint4(addbf2(ua1.x, ub1.x), addbf2(ua1.y, ub1.y),
                                                addbf2(ua1.z, ub1.z), addbf2(ua1.w, ub1.w));
        *(uint4*)&Bsb[sr][skc]     = make_uint4(f2bf2(pb[0].x,pb[0].y), f2bf2(pb[0].z,pb[0].w),
                                                f2bf2(pb[1].x,pb[1].y), f2bf2(pb[1].z,pb[1].w));
        *(uint4*)&Bsb[sr][skc + 8] = make_uint4(f2bf2(pb[2].x,pb[2].y), f2bf2(pb[2].z,pb[2].w),
                                                f2bf2(pb[3].x,pb[3].y), f2bf2(pb[3].z,pb[3].w));
        __syncthreads();
        if (kb + 64 < NQ) {
            ua0 = *(const uint4*)(a0p + kb + 64);
            ua1 = *(const uint4*)(a0p + kb + 64 + 8);
            ub0 = *(const uint4*)(a1p + kb + 64);
            ub1 = *(const uint4*)(a1p + kb + 64 + 8);
#pragma unroll
            for (int i = 0; i < 4; i++) pb[i] = *(const float4*)(bp + kb + 64 + 4 * i);
        }
#pragma unroll
        for (int kk = 0; kk < 2; kk++) {
            v8s a0 = *(const v8s*)&Asb[r0w + n][kk * 32 + quad * 8];
            v8s a1 = *(const v8s*)&Asb[r0w + 16 + n][kk * 32 + quad * 8];
            v8s b0 = *(const v8s*)&Bsb[c0w + n][kk * 32 + quad * 8];
            v8s b1 = *(const v8s*)&Bsb[c0w + 16 + n][kk * 32 + quad * 8];
            acc[0][0] = __builtin_amdgcn_mfma_f32_16x16x32_bf16(a0, b0, acc[0][0], 0, 0, 0);
            acc[0][1] = __builtin_amdgcn_mfma_f32_16x16x32_bf16(a0, b1, acc[0][1], 0, 0, 0);
            acc[1][0] = __builtin_amdgcn_mfma_f32_16x16x32_bf16(a1, b0, acc[1][0], 0, 0, 0);
            acc[1][1] = __builtin_amdgcn_mfma_f32_16x16x32_bf16(a1, b1, acc[1][1], 0, 0, 0);
        }
    }

#pragma unroll
    for (int rt = 0; rt < 2; rt++)
#pragma unroll
        for (int ct = 0; ct < 2; ct++)
#pragma unroll
            for (int reg = 0; reg < 4; reg++) {
                const int row = m0 + r0w + rt * 16 + quad * 4 + reg;
                const int col = n0 + c0w + ct * 16 + n;
                C[(size_t)row * OUTD + col] = acc[rt][ct][reg];
            }
}

// ===========================================================================
extern "C" void kernel_launch(void* const* d_in, const int* in_sizes, int n_in,
                              void* d_out, int out_size, void* d_ws, size_t ws_size,
                              hipStream_t stream) {
    const float* x  = (const float*)d_in[0];
    const float* Wq = (const float*)d_in[1];
    const float* Wk = (const float*)d_in[2];
    const float* Wv = (const float*)d_in[3];
    const float* Wo = (const float*)d_in[4];
    float* out = (float*)d_out;

    // ws: Qg 4MB @0; Kg 1MB @4194304; Vg 1MB @5242880; Oh0 @6291456; Oh1 @10485760
    char* base = (char*)d_ws;
    unsigned short* Qg  = (unsigned short*)(base);
    unsigned short* Kg  = (unsigned short*)(base + 4194304);
    unsigned short* Vg  = (unsigned short*)(base + 5242880);
    unsigned short* Oh0 = (unsigned short*)(base + 6291456);
    unsigned short* Oh1 = (unsigned short*)(base + 10485760);

    dim3 blk(256);
    gemm_qkv<<<dim3(SEQ / 64, (NQ + 2 * NKV) / 64), blk, 0, stream>>>(x, Wq, Wk, Wv, Qg, Kg, Vg);
    attn_mfma<<<dim3(512), blk, 0, stream>>>(Qg, Kg, Vg, Oh0, Oh1);
    gemm_out<<<dim3(SEQ / 64, OUTD / 64), blk, 0, stream>>>(Oh0, Oh1, Wo, out);
}